// Round 13
// baseline (152.844 us; speedup 1.0000x reference)
//
#include <hip/hip_runtime.h>
#include <hip/hip_bf16.h>
#include <hip/hip_fp16.h>

// ---------------- problem constants ----------------
#define N_VEC   16384      // 16*32*32 latent vectors
#define K_CODES 8192
#define D_DIM   256
#define NSPLIT  8          // code-dim splits (grid.y)
#define KT_PER  8          // 1024 cols per split / 128 per kt
#define BM      128

// d_out layout (float32 elements)
#define ZQ_SIZE  (16*256*32*32)          // 4194304
#define DIFF_OFF ZQ_SIZE
#define IDX_OFF  (ZQ_SIZE + 1)
#define PERP_OFF (ZQ_SIZE + 1 + N_VEC)

// ws layout (bytes); ~14.6 MB
#define WS_ENORM 0
#define WS_ZH    65536
#define WS_EH    (WS_ZH + N_VEC * D_DIM * 2)      // +8 MB
#define WS_P2    (WS_EH + K_CODES * D_DIM * 2)    // +4 MB
#define WS_IDXI  (WS_P2 + NSPLIT * N_VEC * 16)    // +2 MB
#define WS_LOSS  (WS_IDXI + N_VEC * 4)            // 4096 floats

typedef _Float16 f16x8 __attribute__((ext_vector_type(8)));
typedef float    f32x4 __attribute__((ext_vector_type(4)));

// monotone (score, idx) 64-bit key: smaller key = smaller score, tie -> smaller idx
__device__ __forceinline__ unsigned long long skey(float s, int c) {
    unsigned u = __float_as_uint(s);
    u ^= (unsigned)((int)u >> 31) | 0x80000000u;
    return ((unsigned long long)u << 13) | (unsigned)c;
}

// Z (A-operand) 16 KB tile: (row 0..127, dloc 0..63 f16), slot = (dloc>>3) ^ (row&7)
__device__ __forceinline__ int swz_off(int row, int dloc) {
    return row * 128 + ((((dloc >> 3) ^ (row & 7))) << 4) + ((dloc & 7) << 1);
}

__device__ __forceinline__ void gload16(const void* g, void* l) {
    __builtin_amdgcn_global_load_lds((const __attribute__((address_space(1))) unsigned int*)g,
                                     (__attribute__((address_space(3))) unsigned int*)l,
                                     16, 0, 0);
}

#define VMW__(n) asm volatile("s_waitcnt vmcnt(" #n ")" ::: "memory")
#define VMW(n) VMW__(n)

// ---------------- kernel 0: fp32 -> fp16 pre-tiled+swizzled, fused codebook norms ----------------
// Z: 16 KB tiles (128 rows x 64 d), slot = (dloc>>3) ^ (row&7)
// E: 8 KB tiles  (128 cols x 32 d), slot = (dloc>>3) ^ ((col>>1)&3)   [BK=32 stage chunks]
__global__ __launch_bounds__(256) void convert_kernel(const float* __restrict__ Z,
                                                      const float* __restrict__ E,
                                                      char* __restrict__ ws) {
    const int t  = threadIdx.x;
    const int r  = blockIdx.x * 4 + (t >> 6);   // one wave per row
    const int d0 = (t & 63) * 4;
    const float* src;
    char* dh;
    const bool isE = (r >= N_VEC);
    if (!isE) {
        src = Z + (size_t)r * D_DIM;
        const int rowl = r & 127;
        dh = ws + WS_ZH + (size_t)(((r >> 7) * 4) + (d0 >> 6)) * 16384
           + swz_off(rowl, d0 & 63);
    } else {
        const int re = r - N_VEC;
        src = E + (size_t)re * D_DIM;
        const int col  = re & 127;
        const int k32  = d0 >> 5;          // 0..7
        const int dloc = d0 & 31;
        const int slot = (dloc >> 3) ^ ((col >> 1) & 3);
        dh = ws + WS_EH + (size_t)((re >> 7) * 8 + k32) * 8192
           + col * 64 + slot * 16 + (dloc & 7) * 2;
    }
    const float4 v = *reinterpret_cast<const float4*>(src + d0);
    const unsigned h0 = __half_as_ushort(__float2half(v.x));
    const unsigned h1 = __half_as_ushort(__float2half(v.y));
    const unsigned h2 = __half_as_ushort(__float2half(v.z));
    const unsigned h3 = __half_as_ushort(__float2half(v.w));
    uint2 hi;
    hi.x = h0 | (h1 << 16);  hi.y = h2 | (h3 << 16);
    *reinterpret_cast<uint2*>(dh) = hi;

    if (isE) {   // fused ||e||^2 (fp32, exact same reduction as all passing rounds)
        float s = v.x * v.x + v.y * v.y + v.z * v.z + v.w * v.w;
        #pragma unroll
        for (int off = 32; off; off >>= 1) s += __shfl_down(s, off);
        if ((t & 63) == 0) ((float*)(ws + WS_ENORM))[r - N_VEC] = s;
    }
}

// ---------------- kernel 1: fp16 MFMA screen; wave-owned rows, A fully in registers
//   (64 VGPR, loaded once), B-only LDS: 4 x 8 KB ring staged 3 steps ahead,
//   counted vmcnt(4) + single barrier per step; enorm in LDS (lgkm, not vmcnt). ----------------
__global__ __launch_bounds__(256, 2) void vq_mfma_kernel(const char* __restrict__ ws_ro,
                                                         ulonglong2* __restrict__ part2) {
    __shared__ short lds[18432];   // B ring: 4 x 4096 shorts (32 KB); enorm: last 4 KB

    const int tid  = threadIdx.x;
    const int lane = tid & 63, wid = tid >> 6;
    const int lane15 = lane & 15, g = lane >> 4;
    const int c13 = (lane15 >> 1) & 3;
    const int bx = blockIdx.x, ksp = blockIdx.y;
    const int row0 = bx * BM;
    const int kbase = ksp * (K_CODES / NSPLIT);
    const int kspBase = ksp * 64;               // global 8KB-chunk index base

    const char* zh = ws_ro + WS_ZH;
    const char* eh = ws_ro + WS_EH;
    short* ring = lds;                          // slot*4096 shorts
    float* enl  = (float*)(lds + 16384);        // 1024 floats

    // stage one 8 KB B chunk sc_ (= kt*8 + j) into ring slot slot_
    #define STAGE_SC(sc_, slot_)                                                       \
    do {                                                                               \
        const char* sB = eh + (size_t)(kspBase + (sc_)) * 8192 + wid * 2048 + lane * 16; \
        short* dB = ring + (slot_) * 4096 + wid * 1024 + lane * 8;                     \
        gload16(sB, dB);                                                               \
        gload16(sB + 1024, dB + 512);                                                  \
    } while (0)

    // ---- resident A: this wave's 32 rows x 256 d = 16 f16x8 = 64 VGPR, loaded once ----
    f16x8 areg[8][2];   // [j (32-d step)][m]
    {
        const char* tileA = zh + (size_t)bx * 65536;
        #pragma unroll
        for (int j = 0; j < 8; ++j)
            #pragma unroll
            for (int m = 0; m < 2; ++m) {
                const int row  = wid * 32 + m * 16 + lane15;
                const int slot = (((j & 1) * 4 + g)) ^ (row & 7);
                areg[j][m] = *reinterpret_cast<const f16x8*>(
                    tileA + (j >> 1) * 16384 + row * 128 + (slot << 4));
            }
    }
    // enorm slice -> LDS (4 KB), ordered BEFORE the B stages (sched_barrier pins issue
    // order so VMW(6) below provably retires A + enl before leaving stages 0..2 in flight)
    gload16((const char*)(ws_ro + WS_ENORM) + ksp * 4096 + wid * 1024 + lane * 16,
            (char*)enl + wid * 1024 + lane * 16);
    __builtin_amdgcn_sched_barrier(0);
    STAGE_SC(0, 0);
    STAGE_SC(1, 1);
    STAGE_SC(2, 2);
    #pragma unroll
    for (int j = 0; j < 8; ++j)
        #pragma unroll
        for (int m = 0; m < 2; ++m)
            asm volatile("" : "+v"(areg[j][m]));   // keep A resident

    // B fragment LDS short-offsets: col = n*16 + lane15 (cols 0..127)
    int colterm[8];
    #pragma unroll
    for (int n = 0; n < 8; ++n) colterm[n] = (n * 16 + lane15) * 32;
    const int sb = (g ^ c13) * 8;   // swizzle slot term (shorts)

    float bestv[8];
    int   bestc[8];
    #pragma unroll
    for (int i = 0; i < 8; ++i) { bestv[i] = 3.0e38f; bestc[i] = 0; }

    VMW(6);                          // retire A + enl (stages 0..2 = 6 loads may remain)
    __builtin_amdgcn_s_barrier();    // all waves' enl parts landed
    __builtin_amdgcn_sched_barrier(0);

    // step: wait own stage(s) landed [vmcnt: oldest-first, over-wait-safe], barrier
    // (=> ALL waves' parts landed AND all prior-step ds_reads retired), read frags,
    // issue stage(s+3), MFMA burst. Stage has ~3 steps of latency cover.
    #define STEP(j_, c_)                                                               \
    do {                                                                               \
        VMW(c_);                                                                       \
        __builtin_amdgcn_s_barrier();                                                  \
        __builtin_amdgcn_sched_barrier(0);                                             \
        f16x8 bf[8];                                                                   \
        _Pragma("unroll")                                                              \
        for (int n_ = 0; n_ < 8; ++n_)                                                 \
            bf[n_] = *reinterpret_cast<const f16x8*>(ring + ((j_) & 3) * 4096          \
                                                     + colterm[n_] + sb);              \
        const int sc_ = kt * 8 + (j_) + 3;                                             \
        if (sc_ < 64) STAGE_SC(sc_, ((j_) + 3) & 3);                                   \
        __builtin_amdgcn_s_setprio(1);                                                 \
        _Pragma("unroll")                                                              \
        for (int m_ = 0; m_ < 2; ++m_)                                                 \
            _Pragma("unroll")                                                          \
            for (int n_ = 0; n_ < 8; ++n_)                                             \
                acc[m_][n_] = __builtin_amdgcn_mfma_f32_16x16x32_f16(                  \
                    areg[j_][m_], bf[n_], acc[m_][n_], 0, 0, 0);                       \
        __builtin_amdgcn_s_setprio(0);                                                 \
    } while (0)

    for (int kt = 0; kt < KT_PER; ++kt) {
        float en_r[8];
        #pragma unroll
        for (int n = 0; n < 8; ++n) en_r[n] = enl[kt * 128 + n * 16 + lane15];

        f32x4 acc[2][8];
        #pragma unroll
        for (int m = 0; m < 2; ++m)
            #pragma unroll
            for (int n = 0; n < 8; ++n)
                #pragma unroll
                for (int q = 0; q < 4; ++q) acc[m][n][q] = 0.0f;

        STEP(0, 4); STEP(1, 4); STEP(2, 4);
        STEP(3, 4); STEP(4, 4); STEP(5, 4);
        if (kt < KT_PER - 1) { STEP(6, 4); STEP(7, 4); }
        else                 { STEP(6, 2); STEP(7, 0); }   // tail: fewer stages in flight

        // fold: score = ||e||^2 - 2 z.e ; (kt, n) ascending scan -> first-min kept
        #pragma unroll
        for (int m = 0; m < 2; ++m)
            #pragma unroll
            for (int n = 0; n < 8; ++n) {
                const int c = kbase + kt * 128 + n * 16 + lane15;
                #pragma unroll
                for (int q = 0; q < 4; ++q) {
                    const int sl = m * 4 + q;
                    const float s = fmaf(-2.0f, acc[m][n][q], en_r[n]);
                    if (s < bestv[sl]) { bestv[sl] = s; bestc[sl] = c; }
                }
            }
    }
    #undef STEP
    #undef STAGE_SC

    // tail: wave owns its rows -> per-row top-2 over the 16 lane15 lanes, direct write
    #pragma unroll
    for (int sl = 0; sl < 8; ++sl) {
        const int m = sl >> 2, q = sl & 3;
        const unsigned long long k1 = skey(bestv[sl], bestc[sl]);
        unsigned long long m1 = k1;
        #pragma unroll
        for (int msk = 1; msk < 16; msk <<= 1) {
            const unsigned long long o = __shfl_xor(m1, msk);
            m1 = (o < m1) ? o : m1;
        }
        unsigned long long k2 = (k1 == m1) ? ~0ull : k1;
        #pragma unroll
        for (int msk = 1; msk < 16; msk <<= 1) {
            const unsigned long long o = __shfl_xor(k2, msk);
            k2 = (o < k2) ? o : k2;
        }
        if (lane15 == 0) {
            const int row = row0 + wid * 32 + m * 16 + g * 4 + q;  // C/D: row=(lane>>4)*4+q
            ulonglong2 res;  res.x = m1;  res.y = k2;
            part2[(size_t)ksp * N_VEC + row] = res;
        }
    }
}

// ---------------- kernel 2: merge splits + exact fp64 rescore of global top-4 + loss ----------------
__global__ __launch_bounds__(256) void rescore_kernel(const float* __restrict__ Z,
                                                      const float* __restrict__ E,
                                                      const ulonglong2* __restrict__ part2,
                                                      int* __restrict__ idx_i,
                                                      float* __restrict__ out_idx,
                                                      float* __restrict__ lossp) {
    __shared__ double redl[4];
    const int tid = threadIdx.x, lane = tid & 63, wid = tid >> 6;
    const int r = blockIdx.x * 4 + wid;
    int c0 = 0, c1 = 0, c2 = 0, c3 = 0;
    if (lane == 0) {
        unsigned long long m0 = ~0ull, m1 = ~0ull, m2 = ~0ull, m3 = ~0ull;
        for (int s = 0; s < NSPLIT; ++s) {
            const ulonglong2 p = part2[(size_t)s * N_VEC + r];
            unsigned long long k = p.x;
            if (k < m0) { m3 = m2; m2 = m1; m1 = m0; m0 = k; }
            else if (k < m1) { m3 = m2; m2 = m1; m1 = k; }
            else if (k < m2) { m3 = m2; m2 = k; }
            else if (k < m3) { m3 = k; }
            k = p.y;
            if (k < m0) { m3 = m2; m2 = m1; m1 = m0; m0 = k; }
            else if (k < m1) { m3 = m2; m2 = m1; m1 = k; }
            else if (k < m2) { m3 = m2; m2 = k; }
            else if (k < m3) { m3 = k; }
        }
        c0 = (int)(m0 & 0x1FFFull);  c1 = (int)(m1 & 0x1FFFull);
        c2 = (int)(m2 & 0x1FFFull);  c3 = (int)(m3 & 0x1FFFull);
    }
    c0 = __shfl(c0, 0);  c1 = __shfl(c1, 0);
    c2 = __shfl(c2, 0);  c3 = __shfl(c3, 0);
    const float4 z4 = *reinterpret_cast<const float4*>(Z + (size_t)r * D_DIM + lane * 4);
    double d[4];
    const int cc[4] = {c0, c1, c2, c3};
    #pragma unroll
    for (int j = 0; j < 4; ++j) {
        const float4 e4 = *reinterpret_cast<const float4*>(E + (size_t)cc[j] * D_DIM + lane * 4);
        const double ax = (double)z4.x - (double)e4.x, ay = (double)z4.y - (double)e4.y;
        const double az = (double)z4.z - (double)e4.z, aw = (double)z4.w - (double)e4.w;
        d[j] = ax * ax + ay * ay + az * az + aw * aw;
    }
    #pragma unroll
    for (int off = 1; off < 64; off <<= 1) {
        #pragma unroll
        for (int j = 0; j < 4; ++j) d[j] += __shfl_xor(d[j], off);
    }
    if (lane == 0) {
        double bd = d[0];  int bi = c0;
        #pragma unroll
        for (int j = 1; j < 4; ++j) {
            if (d[j] < bd || (d[j] == bd && cc[j] < bi)) { bd = d[j]; bi = cc[j]; }
        }
        idx_i[r]   = bi;
        out_idx[r] = (float)bi;
        redl[wid]  = bd;            // exact ||z - zq||^2 of the chosen code
    }
    __syncthreads();
    if (tid == 0) lossp[blockIdx.x] = (float)(redl[0] + redl[1] + redl[2] + redl[3]);
}

// ---------------- kernel 3: gather + NCHW transpose ----------------
__global__ __launch_bounds__(256) void gather_kernel(const float* __restrict__ E,
                                                     const int* __restrict__ idx_i,
                                                     float* __restrict__ out) {
    __shared__ float Ls[128 * 65];
    __shared__ int   sIdx[64];

    const int tid = threadIdx.x;
    const int gb  = blockIdx.x;       // 0..255, 64 latent vectors each
    const int n0  = gb * 64;
    const int b   = n0 >> 10;
    const int hwbase = n0 & 1023;

    if (tid < 64) sIdx[tid] = idx_i[n0 + tid];
    __syncthreads();

    for (int h = 0; h < 2; ++h) {
        if (h) __syncthreads();
        const int rowl = tid >> 2;
        const int qs   = tid & 3;
        const float* erow = E + (size_t)sIdx[rowl] * D_DIM + h * 128;
        #pragma unroll
        for (int m = 0; m < 8; ++m) {
            const int c4 = m * 4 + qs;
            const float4 v = *reinterpret_cast<const float4*>(erow + c4 * 4);
            Ls[(c4 * 4 + 0) * 65 + rowl] = v.x;
            Ls[(c4 * 4 + 1) * 65 + rowl] = v.y;
            Ls[(c4 * 4 + 2) * 65 + rowl] = v.z;
            Ls[(c4 * 4 + 3) * 65 + rowl] = v.w;
        }
        __syncthreads();
        const int wl   = tid & 63;
        const int csub = tid >> 6;
        #pragma unroll
        for (int pc = 0; pc < 32; ++pc) {
            const int c_l = pc * 4 + csub;
            const int c   = h * 128 + c_l;
            out[((size_t)(b * 256 + c)) * 1024 + hwbase + wl] = Ls[c_l * 65 + wl];
        }
    }
}

// ---------------- kernel 4: finalize scalars ----------------
__global__ __launch_bounds__(256) void final_kernel(const float* __restrict__ lossp,
                                                    float* __restrict__ out) {
    __shared__ float red[4];
    const int tid = threadIdx.x;
    float s = 0.0f;
    for (int i = tid; i < N_VEC / 4; i += 256) s += lossp[i];
    #pragma unroll
    for (int off = 32; off; off >>= 1) s += __shfl_down(s, off);
    if ((tid & 63) == 0) red[tid >> 6] = s;
    __syncthreads();
    if (tid == 0) {
        const float total = red[0] + red[1] + red[2] + red[3];
        out[DIFF_OFF] = 0.25f * (total / (float)(N_VEC * D_DIM));
        out[PERP_OFF] = 1.0f;
    }
}

// ---------------- launcher ----------------
extern "C" void kernel_launch(void* const* d_in, const int* in_sizes, int n_in,
                              void* d_out, int out_size, void* d_ws, size_t ws_size,
                              hipStream_t stream) {
    const float* Z = (const float*)d_in[0];   // (16,32,32,256) fp32
    const float* E = (const float*)d_in[1];   // (8192,256) fp32
    float* out = (float*)d_out;
    char*  ws  = (char*)d_ws;                 // needs ~14.6 MB

    ulonglong2* part2   = (ulonglong2*)(ws + WS_P2);
    int*        idx_i   = (int*)(ws + WS_IDXI);
    float*      lossbuf = (float*)(ws + WS_LOSS);

    hipLaunchKernelGGL(convert_kernel, dim3((N_VEC + K_CODES) / 4), dim3(256), 0, stream, Z, E, ws);
    hipLaunchKernelGGL(vq_mfma_kernel, dim3(N_VEC / BM, NSPLIT), dim3(256), 0, stream,
                       (const char*)ws, part2);
    hipLaunchKernelGGL(rescore_kernel, dim3(N_VEC / 4), dim3(256), 0, stream,
                       Z, E, part2, idx_i, out + IDX_OFF, lossbuf);
    hipLaunchKernelGGL(gather_kernel, dim3(N_VEC / 64), dim3(256), 0, stream,
                       E, idx_i, out);
    hipLaunchKernelGGL(final_kernel, dim3(1), dim3(256), 0, stream, lossbuf, out);
}

// Round 15
// 147.333 us; speedup vs baseline: 1.0374x; 1.0374x over previous
//
#include <hip/hip_runtime.h>
#include <hip/hip_bf16.h>
#include <hip/hip_fp16.h>

// ---------------- problem constants ----------------
#define N_VEC   16384      // 16*32*32 latent vectors
#define K_CODES 8192
#define D_DIM   256
#define NSPLIT  8          // code-dim splits (grid.y)
#define BM      128

// d_out layout (float32 elements)
#define ZQ_SIZE  (16*256*32*32)          // 4194304
#define DIFF_OFF ZQ_SIZE
#define IDX_OFF  (ZQ_SIZE + 1)
#define PERP_OFF (ZQ_SIZE + 1 + N_VEC)

// ws layout (bytes); ~14.6 MB
#define WS_ENORM 0
#define WS_ZH    65536
#define WS_EH    (WS_ZH + N_VEC * D_DIM * 2)      // +8 MB
#define WS_P2    (WS_EH + K_CODES * D_DIM * 2)    // +4 MB
#define WS_IDXI  (WS_P2 + NSPLIT * N_VEC * 16)    // +2 MB
#define WS_LOSS  (WS_IDXI + N_VEC * 4)            // 4096 floats

typedef _Float16 f16x8 __attribute__((ext_vector_type(8)));
typedef float    f32x4 __attribute__((ext_vector_type(4)));

// monotone (score, idx) 64-bit key: smaller key = smaller score, tie -> smaller idx
__device__ __forceinline__ unsigned long long skey(float s, int c) {
    unsigned u = __float_as_uint(s);
    u ^= (unsigned)((int)u >> 31) | 0x80000000u;
    return ((unsigned long long)u << 13) | (unsigned)c;
}

// Z (A-operand) 16 KB tile: (row 0..127, dloc 0..63 f16), slot = (dloc>>3) ^ (row&7)
__device__ __forceinline__ int swz_off(int row, int dloc) {
    return row * 128 + ((((dloc >> 3) ^ (row & 7))) << 4) + ((dloc & 7) << 1);
}

__device__ __forceinline__ void gload16(const void* g, void* l) {
    __builtin_amdgcn_global_load_lds((const __attribute__((address_space(1))) unsigned int*)g,
                                     (__attribute__((address_space(3))) unsigned int*)l,
                                     16, 0, 0);
}

#define VMW__(n) asm volatile("s_waitcnt vmcnt(" #n ")" ::: "memory")
#define VMW(n) VMW__(n)

// ---------------- kernel 0: fp32 -> fp16 pre-tiled+swizzled, fused codebook norms ----------------
// Z: 16 KB tiles (128 rows x 64 d), slot = (dloc>>3) ^ (row&7)
// E: 8 KB tiles  (128 cols x 32 d), slot = (dloc>>3) ^ ((col>>1)&3)   [BK=32 stage chunks]
__global__ __launch_bounds__(256) void convert_kernel(const float* __restrict__ Z,
                                                      const float* __restrict__ E,
                                                      char* __restrict__ ws) {
    const int t  = threadIdx.x;
    const int r  = blockIdx.x * 4 + (t >> 6);   // one wave per row
    const int d0 = (t & 63) * 4;
    const float* src;
    char* dh;
    const bool isE = (r >= N_VEC);
    if (!isE) {
        src = Z + (size_t)r * D_DIM;
        const int rowl = r & 127;
        dh = ws + WS_ZH + (size_t)(((r >> 7) * 4) + (d0 >> 6)) * 16384
           + swz_off(rowl, d0 & 63);
    } else {
        const int re = r - N_VEC;
        src = E + (size_t)re * D_DIM;
        const int col  = re & 127;
        const int k32  = d0 >> 5;          // 0..7
        const int dloc = d0 & 31;
        const int slot = (dloc >> 3) ^ ((col >> 1) & 3);
        dh = ws + WS_EH + (size_t)((re >> 7) * 8 + k32) * 8192
           + col * 64 + slot * 16 + (dloc & 7) * 2;
    }
    const float4 v = *reinterpret_cast<const float4*>(src + d0);
    const unsigned h0 = __half_as_ushort(__float2half(v.x));
    const unsigned h1 = __half_as_ushort(__float2half(v.y));
    const unsigned h2 = __half_as_ushort(__float2half(v.z));
    const unsigned h3 = __half_as_ushort(__float2half(v.w));
    uint2 hi;
    hi.x = h0 | (h1 << 16);  hi.y = h2 | (h3 << 16);
    *reinterpret_cast<uint2*>(dh) = hi;

    if (isE) {   // fused ||e||^2 (fp32, exact same reduction as all passing rounds)
        float s = v.x * v.x + v.y * v.y + v.z * v.z + v.w * v.w;
        #pragma unroll
        for (int off = 32; off; off >>= 1) s += __shfl_down(s, off);
        if ((t & 63) == 0) ((float*)(ws + WS_ENORM))[r - N_VEC] = s;
    }
}

// ---------------- kernel 1: fp16 MFMA screen; 512 threads (8 waves), 1 block/CU.
//   A static in LDS (64 KB, staged once); B 3-slot ring of 16 KB chunks staged
//   2 steps ahead -> per-step wait is vmcnt(2) (over-wait-safe), single barrier. ----------------
__global__ __launch_bounds__(512, 2) void vq_mfma_kernel(const char* __restrict__ ws_ro,
                                                         ulonglong2* __restrict__ part2) {
    __shared__ short lds[59392];   // A: [0,32768) | ring: [32768,57344) 3x8192 | enl: [57344,59392)

    const int tid  = threadIdx.x;
    const int lane = tid & 63, wid = tid >> 6;
    const int lane15 = lane & 15, g = lane >> 4;
    const int l7  = lane15 & 7;
    const int wm = wid >> 2, wn = wid & 3;
    const int bx = blockIdx.x, ksp = blockIdx.y;
    const int row0 = bx * BM;
    const int kbase = ksp * (K_CODES / NSPLIT);

    const char* zh = ws_ro + WS_ZH;
    const char* eh = ws_ro + WS_EH;
    short* ring = lds + 32768;
    float* enl  = (float*)(lds + 57344);   // 1024 floats

    // chunk sc = cg*8 + j (0..31): 256 cols x 32 d = 16 KB = two 8 KB E tiles
    // tile(half) = (ksp*8 + cg*2 + half)*8 + j  -> half1 = half0 + 64 KB
    #define STAGE_SC(sc_, slot_)                                                       \
    do {                                                                               \
        if ((sc_) < 32) {                                                              \
            const int cg_ = (sc_) >> 3, j_ = (sc_) & 7;                                \
            const char* s0 = eh + (size_t)(((ksp * 8 + cg_ * 2) * 8) + j_) * 8192      \
                                + wid * 1024 + lane * 16;                              \
            short* d_ = ring + (slot_) * 8192 + wid * 512 + lane * 8;                  \
            gload16(s0, d_);                                                           \
            gload16(s0 + 65536, d_ + 4096);                                            \
        }                                                                              \
    } while (0)

    // ---- prologue: A (64 KB linear, 8 gloads/wave) -> enorm (1, benign dup) -> stages 0,1 ----
    {
        const char* srcA = zh + (size_t)bx * 65536 + wid * 8192 + lane * 16;
        short* dA = lds + wid * 4096 + lane * 8;
        #pragma unroll
        for (int i = 0; i < 8; ++i) gload16(srcA + i * 1024, dA + i * 512);
    }
    gload16((const char*)(ws_ro + WS_ENORM) + ksp * 4096 + (wid & 3) * 1024 + lane * 16,
            (char*)enl + (wid & 3) * 1024 + lane * 16);
    __builtin_amdgcn_sched_barrier(0);
    STAGE_SC(0, 0);
    STAGE_SC(1, 1);

    // loop-invariant fragment offset pieces (shorts)
    int rowterm[4];
    #pragma unroll
    for (int m = 0; m < 4; ++m) rowterm[m] = (wm * 64 + m * 16 + lane15) * 64;
    const int sa0 = (g ^ l7) * 8;        // A slot term, j even; j odd -> ^32
    int boff[4];                          // B frag offset within a ring slot
    #pragma unroll
    for (int n = 0; n < 4; ++n) {
        const int cl   = wn * 64 + n * 16 + lane15;     // 0..255
        const int c127 = cl & 127;
        boff[n] = (cl >> 7) * 4096 + c127 * 32 + ((g ^ ((c127 >> 1) & 3)) << 3);
    }

    float bestv[16];
    int   bestc[16];
    #pragma unroll
    for (int i = 0; i < 16; ++i) { bestv[i] = 3.0e38f; bestc[i] = 0; }

    VMW(2);                          // A + enorm + stage0 landed (stage1 may be in flight)
    __builtin_amdgcn_s_barrier();
    __builtin_amdgcn_sched_barrier(0);

    // step s: wait vmcnt(2) [stage(s) landed; stage(s+1) may fly], barrier, read frags,
    // issue stage(s+2) into slot (s+2)%3 (safe: slot (s-1)%3 reads retired pre-barrier),
    // MFMA burst. s==31 -> vmcnt(0) (stage31 is the only outstanding, issued 2 steps ago).
    // (const int s_: cg-loop is #pragma unroll'd, so s_, %3 indices, and the tail
    //  branch all constant-fold — r14's constexpr failed on the runtime loop var.)
    #define STEP(cg_, j_)                                                              \
    do {                                                                               \
        const int s_ = (cg_) * 8 + (j_);                                               \
        if (s_ == 31) { VMW(0); } else { VMW(2); }                                     \
        __builtin_amdgcn_s_barrier();                                                  \
        __builtin_amdgcn_sched_barrier(0);                                             \
        f16x8 af[4], bf[4];                                                            \
        const int abase = ((j_) >> 1) * 8192 + (sa0 ^ (((j_) & 1) << 5));              \
        const int bbase = (s_ % 3) * 8192;                                             \
        _Pragma("unroll")                                                              \
        for (int m_ = 0; m_ < 4; ++m_)                                                 \
            af[m_] = *reinterpret_cast<const f16x8*>(lds + abase + rowterm[m_]);       \
        _Pragma("unroll")                                                              \
        for (int n_ = 0; n_ < 4; ++n_)                                                 \
            bf[n_] = *reinterpret_cast<const f16x8*>(ring + bbase + boff[n_]);         \
        STAGE_SC(s_ + 2, (s_ + 2) % 3);                                                \
        __builtin_amdgcn_s_setprio(1);                                                 \
        _Pragma("unroll")                                                              \
        for (int m_ = 0; m_ < 4; ++m_)                                                 \
            _Pragma("unroll")                                                          \
            for (int n_ = 0; n_ < 4; ++n_)                                             \
                acc[m_][n_] = __builtin_amdgcn_mfma_f32_16x16x32_f16(                  \
                    af[m_], bf[n_], acc[m_][n_], 0, 0, 0);                             \
        __builtin_amdgcn_s_setprio(0);                                                 \
    } while (0)

    #pragma unroll
    for (int cg = 0; cg < 4; ++cg) {
        f32x4 acc[4][4];
        #pragma unroll
        for (int m = 0; m < 4; ++m)
            #pragma unroll
            for (int n = 0; n < 4; ++n)
                #pragma unroll
                for (int q = 0; q < 4; ++q) acc[m][n][q] = 0.0f;

        STEP(cg, 0); STEP(cg, 1); STEP(cg, 2); STEP(cg, 3);
        STEP(cg, 4); STEP(cg, 5); STEP(cg, 6); STEP(cg, 7);

        // fold: score = ||e||^2 - 2 z.e ; (cg, n) ascending scan -> first-min kept
        #pragma unroll
        for (int m = 0; m < 4; ++m)
            #pragma unroll
            for (int n = 0; n < 4; ++n) {
                const int cl = cg * 256 + wn * 64 + n * 16 + lane15;
                const int c  = kbase + cl;
                const float en = enl[cl];
                #pragma unroll
                for (int q = 0; q < 4; ++q) {
                    const int sl = m * 4 + q;
                    const float s = fmaf(-2.0f, acc[m][n][q], en);
                    if (s < bestv[sl]) { bestv[sl] = s; bestc[sl] = c; }
                }
            }
    }
    #undef STEP
    #undef STAGE_SC

    // tail: per-wave top-2 per row over 16 lane15-lanes, then merge the 4 wn-waves via LDS
    __syncthreads();
    unsigned long long* t2 = reinterpret_cast<unsigned long long*>(lds);  // [wid][64][2]
    #pragma unroll
    for (int sl = 0; sl < 16; ++sl) {
        const int m = sl >> 2, q = sl & 3;
        const unsigned long long k1 = skey(bestv[sl], bestc[sl]);
        unsigned long long m1 = k1;
        #pragma unroll
        for (int msk = 1; msk < 16; msk <<= 1) {
            const unsigned long long o = __shfl_xor(m1, msk);
            m1 = (o < m1) ? o : m1;
        }
        unsigned long long k2 = (k1 == m1) ? ~0ull : k1;
        #pragma unroll
        for (int msk = 1; msk < 16; msk <<= 1) {
            const unsigned long long o = __shfl_xor(k2, msk);
            k2 = (o < k2) ? o : k2;
        }
        if (lane15 == 0) {
            const int row64 = m * 16 + g * 4 + q;
            t2[(wid * 64 + row64) * 2 + 0] = m1;
            t2[(wid * 64 + row64) * 2 + 1] = k2;
        }
    }
    __syncthreads();
    if (tid < 128) {
        const int wmg = tid >> 6, r64 = tid & 63;
        unsigned long long m0 = ~0ull, m1 = ~0ull;
        #pragma unroll
        for (int w = 0; w < 4; ++w) {
            #pragma unroll
            for (int k = 0; k < 2; ++k) {
                const unsigned long long key = t2[(((wmg * 4 + w) * 64) + r64) * 2 + k];
                if (key < m0) { m1 = m0; m0 = key; }
                else if (key < m1) { m1 = key; }
            }
        }
        ulonglong2 res;  res.x = m0;  res.y = m1;
        part2[(size_t)ksp * N_VEC + row0 + wmg * 64 + r64] = res;
    }
}

// ---------------- kernel 2: merge splits + exact fp64 rescore of global top-4 + loss ----------------
__global__ __launch_bounds__(256) void rescore_kernel(const float* __restrict__ Z,
                                                      const float* __restrict__ E,
                                                      const ulonglong2* __restrict__ part2,
                                                      int* __restrict__ idx_i,
                                                      float* __restrict__ out_idx,
                                                      float* __restrict__ lossp) {
    __shared__ double redl[4];
    const int tid = threadIdx.x, lane = tid & 63, wid = tid >> 6;
    const int r = blockIdx.x * 4 + wid;
    int c0 = 0, c1 = 0, c2 = 0, c3 = 0;
    if (lane == 0) {
        unsigned long long m0 = ~0ull, m1 = ~0ull, m2 = ~0ull, m3 = ~0ull;
        for (int s = 0; s < NSPLIT; ++s) {
            const ulonglong2 p = part2[(size_t)s * N_VEC + r];
            unsigned long long k = p.x;
            if (k < m0) { m3 = m2; m2 = m1; m1 = m0; m0 = k; }
            else if (k < m1) { m3 = m2; m2 = m1; m1 = k; }
            else if (k < m2) { m3 = m2; m2 = k; }
            else if (k < m3) { m3 = k; }
            k = p.y;
            if (k < m0) { m3 = m2; m2 = m1; m1 = m0; m0 = k; }
            else if (k < m1) { m3 = m2; m2 = m1; m1 = k; }
            else if (k < m2) { m3 = m2; m2 = k; }
            else if (k < m3) { m3 = k; }
        }
        c0 = (int)(m0 & 0x1FFFull);  c1 = (int)(m1 & 0x1FFFull);
        c2 = (int)(m2 & 0x1FFFull);  c3 = (int)(m3 & 0x1FFFull);
    }
    c0 = __shfl(c0, 0);  c1 = __shfl(c1, 0);
    c2 = __shfl(c2, 0);  c3 = __shfl(c3, 0);
    const float4 z4 = *reinterpret_cast<const float4*>(Z + (size_t)r * D_DIM + lane * 4);
    double d[4];
    const int cc[4] = {c0, c1, c2, c3};
    #pragma unroll
    for (int j = 0; j < 4; ++j) {
        const float4 e4 = *reinterpret_cast<const float4*>(E + (size_t)cc[j] * D_DIM + lane * 4);
        const double ax = (double)z4.x - (double)e4.x, ay = (double)z4.y - (double)e4.y;
        const double az = (double)z4.z - (double)e4.z, aw = (double)z4.w - (double)e4.w;
        d[j] = ax * ax + ay * ay + az * az + aw * aw;
    }
    #pragma unroll
    for (int off = 1; off < 64; off <<= 1) {
        #pragma unroll
        for (int j = 0; j < 4; ++j) d[j] += __shfl_xor(d[j], off);
    }
    if (lane == 0) {
        double bd = d[0];  int bi = c0;
        #pragma unroll
        for (int j = 1; j < 4; ++j) {
            if (d[j] < bd || (d[j] == bd && cc[j] < bi)) { bd = d[j]; bi = cc[j]; }
        }
        idx_i[r]   = bi;
        out_idx[r] = (float)bi;
        redl[wid]  = bd;            // exact ||z - zq||^2 of the chosen code
    }
    __syncthreads();
    if (tid == 0) lossp[blockIdx.x] = (float)(redl[0] + redl[1] + redl[2] + redl[3]);
}

// ---------------- kernel 3: gather + NCHW transpose ----------------
__global__ __launch_bounds__(256) void gather_kernel(const float* __restrict__ E,
                                                     const int* __restrict__ idx_i,
                                                     float* __restrict__ out) {
    __shared__ float Ls[128 * 65];
    __shared__ int   sIdx[64];

    const int tid = threadIdx.x;
    const int gb  = blockIdx.x;       // 0..255, 64 latent vectors each
    const int n0  = gb * 64;
    const int b   = n0 >> 10;
    const int hwbase = n0 & 1023;

    if (tid < 64) sIdx[tid] = idx_i[n0 + tid];
    __syncthreads();

    for (int h = 0; h < 2; ++h) {
        if (h) __syncthreads();
        const int rowl = tid >> 2;
        const int qs   = tid & 3;
        const float* erow = E + (size_t)sIdx[rowl] * D_DIM + h * 128;
        #pragma unroll
        for (int m = 0; m < 8; ++m) {
            const int c4 = m * 4 + qs;
            const float4 v = *reinterpret_cast<const float4*>(erow + c4 * 4);
            Ls[(c4 * 4 + 0) * 65 + rowl] = v.x;
            Ls[(c4 * 4 + 1) * 65 + rowl] = v.y;
            Ls[(c4 * 4 + 2) * 65 + rowl] = v.z;
            Ls[(c4 * 4 + 3) * 65 + rowl] = v.w;
        }
        __syncthreads();
        const int wl   = tid & 63;
        const int csub = tid >> 6;
        #pragma unroll
        for (int pc = 0; pc < 32; ++pc) {
            const int c_l = pc * 4 + csub;
            const int c   = h * 128 + c_l;
            out[((size_t)(b * 256 + c)) * 1024 + hwbase + wl] = Ls[c_l * 65 + wl];
        }
    }
}

// ---------------- kernel 4: finalize scalars ----------------
__global__ __launch_bounds__(256) void final_kernel(const float* __restrict__ lossp,
                                                    float* __restrict__ out) {
    __shared__ float red[4];
    const int tid = threadIdx.x;
    float s = 0.0f;
    for (int i = tid; i < N_VEC / 4; i += 256) s += lossp[i];
    #pragma unroll
    for (int off = 32; off; off >>= 1) s += __shfl_down(s, off);
    if ((tid & 63) == 0) red[tid >> 6] = s;
    __syncthreads();
    if (tid == 0) {
        const float total = red[0] + red[1] + red[2] + red[3];
        out[DIFF_OFF] = 0.25f * (total / (float)(N_VEC * D_DIM));
        out[PERP_OFF] = 1.0f;
    }
}

// ---------------- launcher ----------------
extern "C" void kernel_launch(void* const* d_in, const int* in_sizes, int n_in,
                              void* d_out, int out_size, void* d_ws, size_t ws_size,
                              hipStream_t stream) {
    const float* Z = (const float*)d_in[0];   // (16,32,32,256) fp32
    const float* E = (const float*)d_in[1];   // (8192,256) fp32
    float* out = (float*)d_out;
    char*  ws  = (char*)d_ws;                 // needs ~14.6 MB

    ulonglong2* part2   = (ulonglong2*)(ws + WS_P2);
    int*        idx_i   = (int*)(ws + WS_IDXI);
    float*      lossbuf = (float*)(ws + WS_LOSS);

    hipLaunchKernelGGL(convert_kernel, dim3((N_VEC + K_CODES) / 4), dim3(256), 0, stream, Z, E, ws);
    hipLaunchKernelGGL(vq_mfma_kernel, dim3(N_VEC / BM, NSPLIT), dim3(512), 0, stream,
                       (const char*)ws, part2);
    hipLaunchKernelGGL(rescore_kernel, dim3(N_VEC / 4), dim3(256), 0, stream,
                       Z, E, part2, idx_i, out + IDX_OFF, lossbuf);
    hipLaunchKernelGGL(gather_kernel, dim3(N_VEC / 64), dim3(256), 0, stream,
                       E, idx_i, out);
    hipLaunchKernelGGL(final_kernel, dim3(1), dim3(256), 0, stream, lossbuf, out);
}

// Round 16
// 131.650 us; speedup vs baseline: 1.1610x; 1.1191x over previous
//
#include <hip/hip_runtime.h>
#include <hip/hip_bf16.h>
#include <hip/hip_fp16.h>

// ---------------- problem constants ----------------
#define N_VEC   16384      // 16*32*32 latent vectors
#define K_CODES 8192
#define D_DIM   256
#define NSPLIT  8          // code-dim splits (grid.y)
#define KT_PER  8          // 1024 cols per split / 128 per kt
#define BM      128

// d_out layout (float32 elements)
#define ZQ_SIZE  (16*256*32*32)          // 4194304
#define DIFF_OFF ZQ_SIZE
#define IDX_OFF  (ZQ_SIZE + 1)
#define PERP_OFF (ZQ_SIZE + 1 + N_VEC)

// ws layout (bytes); ~14.6 MB
#define WS_ENORM 0
#define WS_ZH    65536
#define WS_EH    (WS_ZH + N_VEC * D_DIM * 2)      // +8 MB
#define WS_P2    (WS_EH + K_CODES * D_DIM * 2)    // +4 MB
#define WS_IDXI  (WS_P2 + NSPLIT * N_VEC * 16)    // +2 MB
#define WS_LOSS  (WS_IDXI + N_VEC * 4)            // 256 floats used

typedef _Float16 f16x8 __attribute__((ext_vector_type(8)));
typedef float    f32x4 __attribute__((ext_vector_type(4)));

// monotone (score, idx) 64-bit key: smaller key = smaller score, tie -> smaller idx
__device__ __forceinline__ unsigned long long skey(float s, int c) {
    unsigned u = __float_as_uint(s);
    u ^= (unsigned)((int)u >> 31) | 0x80000000u;
    return ((unsigned long long)u << 13) | (unsigned)c;
}

// Z (A-operand) 16 KB tile: (row 0..127, dloc 0..63 f16), slot = (dloc>>3) ^ (row&7)
__device__ __forceinline__ int swz_off(int row, int dloc) {
    return row * 128 + ((((dloc >> 3) ^ (row & 7))) << 4) + ((dloc & 7) << 1);
}

__device__ __forceinline__ void gload16(const void* g, void* l) {
    __builtin_amdgcn_global_load_lds((const __attribute__((address_space(1))) unsigned int*)g,
                                     (__attribute__((address_space(3))) unsigned int*)l,
                                     16, 0, 0);
}

#define VMW__(n) asm volatile("s_waitcnt vmcnt(" #n ")" ::: "memory")
#define VMW(n) VMW__(n)

// ---------------- kernel 0: fp32 -> fp16 pre-tiled+swizzled, fused codebook norms ----------------
// Z: 16 KB tiles (128 rows x 64 d), slot = (dloc>>3) ^ (row&7)
// E: 8 KB tiles  (128 cols x 32 d), slot = (dloc>>3) ^ ((col>>1)&3)   [BK=32 stage chunks]
__global__ __launch_bounds__(256) void convert_kernel(const float* __restrict__ Z,
                                                      const float* __restrict__ E,
                                                      char* __restrict__ ws) {
    const int t  = threadIdx.x;
    const int r  = blockIdx.x * 4 + (t >> 6);   // one wave per row
    const int d0 = (t & 63) * 4;
    const float* src;
    char* dh;
    const bool isE = (r >= N_VEC);
    if (!isE) {
        src = Z + (size_t)r * D_DIM;
        const int rowl = r & 127;
        dh = ws + WS_ZH + (size_t)(((r >> 7) * 4) + (d0 >> 6)) * 16384
           + swz_off(rowl, d0 & 63);
    } else {
        const int re = r - N_VEC;
        src = E + (size_t)re * D_DIM;
        const int col  = re & 127;
        const int k32  = d0 >> 5;          // 0..7
        const int dloc = d0 & 31;
        const int slot = (dloc >> 3) ^ ((col >> 1) & 3);
        dh = ws + WS_EH + (size_t)((re >> 7) * 8 + k32) * 8192
           + col * 64 + slot * 16 + (dloc & 7) * 2;
    }
    const float4 v = *reinterpret_cast<const float4*>(src + d0);
    const unsigned h0 = __half_as_ushort(__float2half(v.x));
    const unsigned h1 = __half_as_ushort(__float2half(v.y));
    const unsigned h2 = __half_as_ushort(__float2half(v.z));
    const unsigned h3 = __half_as_ushort(__float2half(v.w));
    uint2 hi;
    hi.x = h0 | (h1 << 16);  hi.y = h2 | (h3 << 16);
    *reinterpret_cast<uint2*>(dh) = hi;

    if (isE) {   // fused ||e||^2 (fp32, exact same reduction as all passing rounds)
        float s = v.x * v.x + v.y * v.y + v.z * v.z + v.w * v.w;
        #pragma unroll
        for (int off = 32; off; off >>= 1) s += __shfl_down(s, off);
        if ((t & 63) == 0) ((float*)(ws + WS_ENORM))[r - N_VEC] = s;
    }
}

// ---------------- kernel 1: fp16 MFMA screen (r12-exact, best measured 84.5 us):
//   A static in LDS, B dbuf 8 KB chunks; single-barrier phase: vmcnt(0) ->
//   s_barrier -> { ds_read | STAGE next | MFMA } compiler-interleaved. ----------------
__global__ __launch_bounds__(256, 2) void vq_mfma_kernel(const char* __restrict__ ws_ro,
                                                         ulonglong2* __restrict__ part2) {
    __shared__ short lds[40960];   // A: [0,32768) shorts (64 KB); B dbuf: [32768,40960) (16 KB)

    const int tid  = threadIdx.x;
    const int lane = tid & 63, wid = tid >> 6;
    const int lane15 = lane & 15, g = lane >> 4;
    const int l7  = lane15 & 7;
    const int c13 = (lane15 >> 1) & 3;
    const int wm = wid >> 1, wn = wid & 1;
    const int bx = blockIdx.x, ksp = blockIdx.y;
    const int row0 = bx * BM;
    const int kbase = ksp * (K_CODES / NSPLIT);

    const char* zh = ws_ro + WS_ZH;
    const char* eh = ws_ro + WS_EH;
    const float* enorm = (const float*)(ws_ro + WS_ENORM);

    #define STAGE_B(kt_, j_)                                                           \
    do {                                                                               \
        const char* sB = eh + (size_t)(((ksp * 8 + (kt_)) * 8) + (j_)) * 8192          \
                            + wid * 2048 + lane * 16;                                  \
        short* dB = lds + 32768 + ((j_) & 1) * 4096 + wid * 1024 + lane * 8;           \
        gload16(sB, dB);                                                               \
        gload16(sB + 1024, dB + 512);                                                  \
    } while (0)

    {
        const char* srcA = zh + (size_t)bx * 65536 + wid * 16384 + lane * 16;
        short* dA = lds + wid * 8192 + lane * 8;
        #pragma unroll
        for (int i = 0; i < 16; ++i) gload16(srcA + i * 1024, dA + i * 512);
    }
    STAGE_B(0, 0);
    float en_c[4], en_n[4];
    #pragma unroll
    for (int n = 0; n < 4; ++n) en_c[n] = enorm[kbase + wn * 64 + n * 16 + lane15];
    asm volatile("s_waitcnt vmcnt(0)" ::: "memory");
    __builtin_amdgcn_s_barrier();
    __builtin_amdgcn_sched_barrier(0);

    int rowterm[4];
    #pragma unroll
    for (int m = 0; m < 4; ++m) rowterm[m] = (wm * 64 + m * 16 + lane15) * 64;
    int colterm[4];
    #pragma unroll
    for (int n = 0; n < 4; ++n) colterm[n] = (wn * 64 + n * 16 + lane15) * 32;
    const int sa0 = (g ^ l7) * 8;
    const int sb  = (g ^ c13) * 8;

    float bestv[16];
    int   bestc[16];
    #pragma unroll
    for (int i = 0; i < 16; ++i) { bestv[i] = 3.0e38f; bestc[i] = 0; }

    #define STEP(j_)                                                                   \
    do {                                                                               \
        asm volatile("s_waitcnt vmcnt(0)" ::: "memory");                               \
        __builtin_amdgcn_s_barrier();                                                  \
        __builtin_amdgcn_sched_barrier(0);                                             \
        f16x8 af[4], bf[4];                                                            \
        const int abase = ((j_) >> 1) * 8192 + (sa0 ^ (((j_) & 1) << 5));              \
        const int bbase = 32768 + ((j_) & 1) * 4096 + sb;                              \
        _Pragma("unroll")                                                              \
        for (int m = 0; m < 4; ++m)                                                    \
            af[m] = *reinterpret_cast<const f16x8*>(lds + abase + rowterm[m]);         \
        _Pragma("unroll")                                                              \
        for (int n = 0; n < 4; ++n)                                                    \
            bf[n] = *reinterpret_cast<const f16x8*>(lds + bbase + colterm[n]);         \
        if ((j_) < 7) {                                                                \
            STAGE_B(kt, (j_) + 1);                                                     \
        } else if (kt < KT_PER - 1) {                                                  \
            STAGE_B(kt + 1, 0);                                                        \
            _Pragma("unroll")                                                          \
            for (int n = 0; n < 4; ++n)                                                \
                en_n[n] = enorm[kbase + (kt + 1) * 128 + wn * 64 + n * 16 + lane15];   \
        }                                                                              \
        __builtin_amdgcn_s_setprio(1);                                                 \
        _Pragma("unroll")                                                              \
        for (int m = 0; m < 4; ++m)                                                    \
            _Pragma("unroll")                                                          \
            for (int n = 0; n < 4; ++n)                                                \
                acc[m][n] = __builtin_amdgcn_mfma_f32_16x16x32_f16(                    \
                    af[m], bf[n], acc[m][n], 0, 0, 0);                                 \
        __builtin_amdgcn_s_setprio(0);                                                 \
    } while (0)

    for (int kt = 0; kt < KT_PER; ++kt) {
        f32x4 acc[4][4];
        #pragma unroll
        for (int m = 0; m < 4; ++m)
            #pragma unroll
            for (int n = 0; n < 4; ++n)
                #pragma unroll
                for (int q = 0; q < 4; ++q) acc[m][n][q] = 0.0f;

        STEP(0); STEP(1); STEP(2); STEP(3);
        STEP(4); STEP(5); STEP(6); STEP(7);

        #pragma unroll
        for (int m = 0; m < 4; ++m)
            #pragma unroll
            for (int n = 0; n < 4; ++n) {
                const int c = kbase + kt * 128 + wn * 64 + n * 16 + lane15;
                #pragma unroll
                for (int q = 0; q < 4; ++q) {
                    const int sl = m * 4 + q;
                    const float s = fmaf(-2.0f, acc[m][n][q], en_c[n]);
                    if (s < bestv[sl]) { bestv[sl] = s; bestc[sl] = c; }
                }
            }
        #pragma unroll
        for (int n = 0; n < 4; ++n) en_c[n] = en_n[n];
    }
    #undef STEP
    #undef STAGE_B

    // tail: per-row top-2 over the 16 lanes sharing each row (lexicographic keys)
    unsigned long long* t2 = reinterpret_cast<unsigned long long*>(lds);  // [wid][64][2]
    #pragma unroll
    for (int sl = 0; sl < 16; ++sl) {
        const int m = sl >> 2, q = sl & 3;
        const unsigned long long k1 = skey(bestv[sl], bestc[sl]);
        unsigned long long m1 = k1;
        #pragma unroll
        for (int msk = 1; msk < 16; msk <<= 1) {
            const unsigned long long o = __shfl_xor(m1, msk);
            m1 = (o < m1) ? o : m1;
        }
        unsigned long long k2 = (k1 == m1) ? ~0ull : k1;
        #pragma unroll
        for (int msk = 1; msk < 16; msk <<= 1) {
            const unsigned long long o = __shfl_xor(k2, msk);
            k2 = (o < k2) ? o : k2;
        }
        if (lane15 == 0) {
            const int row64 = m * 16 + g * 4 + q;
            t2[(wid * 64 + row64) * 2 + 0] = m1;
            t2[(wid * 64 + row64) * 2 + 1] = k2;
        }
    }
    __syncthreads();
    if (tid < 128) {
        const int wm2 = tid >> 6, r64 = tid & 63;
        const unsigned long long a1 = t2[((wm2 * 2 + 0) * 64 + r64) * 2 + 0];
        const unsigned long long a2 = t2[((wm2 * 2 + 0) * 64 + r64) * 2 + 1];
        const unsigned long long b1 = t2[((wm2 * 2 + 1) * 64 + r64) * 2 + 0];
        const unsigned long long b2 = t2[((wm2 * 2 + 1) * 64 + r64) * 2 + 1];
        const unsigned long long r1 = (a1 < b1) ? a1 : b1;
        const unsigned long long hi = (a1 < b1) ? b1 : a1;
        const unsigned long long l2 = (a2 < b2) ? a2 : b2;
        const unsigned long long r2 = (hi < l2) ? hi : l2;
        ulonglong2 res;  res.x = r1;  res.y = r2;
        part2[(size_t)ksp * N_VEC + row0 + tid] = res;
    }
}

// ---------------- kernel 2: fused epilogue — merge+fp64 rescore + gather/transpose + loss ----
// 256 blocks x 256 threads; block gb owns rows n0..n0+63.
__global__ __launch_bounds__(256) void epilogue_kernel(const float* __restrict__ Z,
                                                       const float* __restrict__ E,
                                                       const ulonglong2* __restrict__ part2,
                                                       float* __restrict__ out,
                                                       float* __restrict__ out_idx,
                                                       float* __restrict__ lossp) {
    __shared__ float  Ls[128 * 65];     // phase C transpose; first 8 KB alias `keys` (A/B)
    __shared__ int    sIdx[64];
    __shared__ double redl[4];
    unsigned long long* keys = reinterpret_cast<unsigned long long*>(Ls);  // [64][16]

    const int tid = threadIdx.x, lane = tid & 63, wid = tid >> 6;
    const int gb = blockIdx.x;
    const int n0 = gb * 64;
    const int b  = n0 >> 10;
    const int hwbase = n0 & 1023;

    // ---- phase A: cooperative part2 load (all 16 keys per row -> same top-4-of-16
    //      candidate guarantee as the passing standalone rescore) ----
    {
        const int r = tid & 63, sp2 = tid >> 6;   // sp2 -> splits 2*sp2, 2*sp2+1
        const ulonglong2 p0 = part2[(size_t)(sp2 * 2 + 0) * N_VEC + n0 + r];
        const ulonglong2 p1 = part2[(size_t)(sp2 * 2 + 1) * N_VEC + n0 + r];
        keys[r * 16 + sp2 * 4 + 0] = p0.x;
        keys[r * 16 + sp2 * 4 + 1] = p0.y;
        keys[r * 16 + sp2 * 4 + 2] = p1.x;
        keys[r * 16 + sp2 * 4 + 3] = p1.y;
    }
    __syncthreads();

    // ---- phase B: per-row top-4 + exact fp64 rescore; wave w -> rows w*16..+15 ----
    double lacc = 0.0;
    for (int i = 0; i < 16; ++i) {
        const int r = wid * 16 + i;
        unsigned long long m0 = ~0ull, m1 = ~0ull, m2 = ~0ull, m3 = ~0ull;
        #pragma unroll
        for (int k = 0; k < 16; ++k) {      // all lanes redundantly (uniform, no divergence)
            const unsigned long long key = keys[r * 16 + k];
            if (key < m0) { m3 = m2; m2 = m1; m1 = m0; m0 = key; }
            else if (key < m1) { m3 = m2; m2 = m1; m1 = key; }
            else if (key < m2) { m3 = m2; m2 = key; }
            else if (key < m3) { m3 = key; }
        }
        const int cc[4] = {(int)(m0 & 0x1FFFull), (int)(m1 & 0x1FFFull),
                           (int)(m2 & 0x1FFFull), (int)(m3 & 0x1FFFull)};
        const float4 z4 = *reinterpret_cast<const float4*>(Z + (size_t)(n0 + r) * D_DIM + lane * 4);
        double d[4];
        #pragma unroll
        for (int j = 0; j < 4; ++j) {
            const float4 e4 = *reinterpret_cast<const float4*>(E + (size_t)cc[j] * D_DIM + lane * 4);
            const double ax = (double)z4.x - (double)e4.x, ay = (double)z4.y - (double)e4.y;
            const double az = (double)z4.z - (double)e4.z, aw = (double)z4.w - (double)e4.w;
            d[j] = ax * ax + ay * ay + az * az + aw * aw;
        }
        #pragma unroll
        for (int off = 1; off < 64; off <<= 1) {
            #pragma unroll
            for (int j = 0; j < 4; ++j) d[j] += __shfl_xor(d[j], off);
        }
        if (lane == 0) {
            double bd = d[0];  int bi = cc[0];
            #pragma unroll
            for (int j = 1; j < 4; ++j) {
                if (d[j] < bd || (d[j] == bd && cc[j] < bi)) { bd = d[j]; bi = cc[j]; }
            }
            out_idx[n0 + r] = (float)bi;
            sIdx[r]         = bi;
            lacc           += bd;           // exact ||z - zq||^2 of chosen code
        }
    }
    if (lane == 0) redl[wid] = lacc;
    __syncthreads();
    if (tid == 0) lossp[gb] = (float)(redl[0] + redl[1] + redl[2] + redl[3]);

    // ---- phase C: gather + NCHW transpose (proven body; idx from LDS, E L2-warm) ----
    for (int h = 0; h < 2; ++h) {
        if (h) __syncthreads();
        const int rowl = tid >> 2;
        const int qs   = tid & 3;
        const float* erow = E + (size_t)sIdx[rowl] * D_DIM + h * 128;
        #pragma unroll
        for (int m = 0; m < 8; ++m) {
            const int c4 = m * 4 + qs;
            const float4 v = *reinterpret_cast<const float4*>(erow + c4 * 4);
            Ls[(c4 * 4 + 0) * 65 + rowl] = v.x;
            Ls[(c4 * 4 + 1) * 65 + rowl] = v.y;
            Ls[(c4 * 4 + 2) * 65 + rowl] = v.z;
            Ls[(c4 * 4 + 3) * 65 + rowl] = v.w;
        }
        __syncthreads();
        const int wl   = tid & 63;
        const int csub = tid >> 6;
        #pragma unroll
        for (int pc = 0; pc < 32; ++pc) {
            const int c_l = pc * 4 + csub;
            const int c   = h * 128 + c_l;
            out[((size_t)(b * 256 + c)) * 1024 + hwbase + wl] = Ls[c_l * 65 + wl];
        }
    }
}

// ---------------- kernel 3: finalize scalars (256 partials) ----------------
__global__ __launch_bounds__(256) void final_kernel(const float* __restrict__ lossp,
                                                    float* __restrict__ out) {
    __shared__ float red[4];
    const int tid = threadIdx.x;
    float s = lossp[tid];
    #pragma unroll
    for (int off = 32; off; off >>= 1) s += __shfl_down(s, off);
    if ((tid & 63) == 0) red[tid >> 6] = s;
    __syncthreads();
    if (tid == 0) {
        const float total = red[0] + red[1] + red[2] + red[3];
        out[DIFF_OFF] = 0.25f * (total / (float)(N_VEC * D_DIM));
        out[PERP_OFF] = 1.0f;
    }
}

// ---------------- launcher ----------------
extern "C" void kernel_launch(void* const* d_in, const int* in_sizes, int n_in,
                              void* d_out, int out_size, void* d_ws, size_t ws_size,
                              hipStream_t stream) {
    const float* Z = (const float*)d_in[0];   // (16,32,32,256) fp32
    const float* E = (const float*)d_in[1];   // (8192,256) fp32
    float* out = (float*)d_out;
    char*  ws  = (char*)d_ws;                 // needs ~14.6 MB

    ulonglong2* part2   = (ulonglong2*)(ws + WS_P2);
    float*      lossbuf = (float*)(ws + WS_LOSS);

    hipLaunchKernelGGL(convert_kernel, dim3((N_VEC + K_CODES) / 4), dim3(256), 0, stream, Z, E, ws);
    hipLaunchKernelGGL(vq_mfma_kernel, dim3(N_VEC / BM, NSPLIT), dim3(256), 0, stream,
                       (const char*)ws, part2);
    hipLaunchKernelGGL(epilogue_kernel, dim3(N_VEC / 64), dim3(256), 0, stream,
                       Z, E, part2, out, out + IDX_OFF, lossbuf);
    hipLaunchKernelGGL(final_kernel, dim3(1), dim3(256), 0, stream, lossbuf, out);
}

// Round 17
// 117.463 us; speedup vs baseline: 1.3012x; 1.1208x over previous
//
#include <hip/hip_runtime.h>
#include <hip/hip_bf16.h>
#include <hip/hip_fp16.h>

// ---------------- problem constants ----------------
#define N_VEC   16384      // 16*32*32 latent vectors
#define K_CODES 8192
#define D_DIM   256
#define NSPLIT  8          // code-dim splits (grid.y)
#define KT_PER  8          // 1024 cols per split / 128 per kt
#define BM      128

// d_out layout (float32 elements)
#define ZQ_SIZE  (16*256*32*32)          // 4194304
#define DIFF_OFF ZQ_SIZE
#define IDX_OFF  (ZQ_SIZE + 1)
#define PERP_OFF (ZQ_SIZE + 1 + N_VEC)

// ws layout (bytes); ~14.6 MB
#define WS_ENORM 0
#define WS_ZH    65536
#define WS_EH    (WS_ZH + N_VEC * D_DIM * 2)      // +8 MB
#define WS_P2    (WS_EH + K_CODES * D_DIM * 2)    // +4 MB
#define WS_IDXI  (WS_P2 + NSPLIT * N_VEC * 16)    // +2 MB
#define WS_LOSS  (WS_IDXI + N_VEC * 4)            // 4096 floats

typedef _Float16 f16x8 __attribute__((ext_vector_type(8)));
typedef float    f32x4 __attribute__((ext_vector_type(4)));

// monotone (score, idx) 64-bit key: smaller key = smaller score, tie -> smaller idx
__device__ __forceinline__ unsigned long long skey(float s, int c) {
    unsigned u = __float_as_uint(s);
    u ^= (unsigned)((int)u >> 31) | 0x80000000u;
    return ((unsigned long long)u << 13) | (unsigned)c;
}

// Z (A-operand) 16 KB tile: (row 0..127, dloc 0..63 f16), slot = (dloc>>3) ^ (row&7)
__device__ __forceinline__ int swz_off(int row, int dloc) {
    return row * 128 + ((((dloc >> 3) ^ (row & 7))) << 4) + ((dloc & 7) << 1);
}

__device__ __forceinline__ void gload16(const void* g, void* l) {
    __builtin_amdgcn_global_load_lds((const __attribute__((address_space(1))) unsigned int*)g,
                                     (__attribute__((address_space(3))) unsigned int*)l,
                                     16, 0, 0);
}

// ---------------- kernel 0: fp32 -> fp16 pre-tiled+swizzled, fused codebook norms ----------------
// Z: 16 KB tiles (128 rows x 64 d), slot = (dloc>>3) ^ (row&7)
// E: 8 KB tiles  (128 cols x 32 d), slot = (dloc>>3) ^ ((col>>1)&3)   [BK=32 stage chunks]
__global__ __launch_bounds__(256) void convert_kernel(const float* __restrict__ Z,
                                                      const float* __restrict__ E,
                                                      char* __restrict__ ws) {
    const int t  = threadIdx.x;
    const int r  = blockIdx.x * 4 + (t >> 6);   // one wave per row
    const int d0 = (t & 63) * 4;
    const float* src;
    char* dh;
    const bool isE = (r >= N_VEC);
    if (!isE) {
        src = Z + (size_t)r * D_DIM;
        const int rowl = r & 127;
        dh = ws + WS_ZH + (size_t)(((r >> 7) * 4) + (d0 >> 6)) * 16384
           + swz_off(rowl, d0 & 63);
    } else {
        const int re = r - N_VEC;
        src = E + (size_t)re * D_DIM;
        const int col  = re & 127;
        const int k32  = d0 >> 5;          // 0..7
        const int dloc = d0 & 31;
        const int slot = (dloc >> 3) ^ ((col >> 1) & 3);
        dh = ws + WS_EH + (size_t)((re >> 7) * 8 + k32) * 8192
           + col * 64 + slot * 16 + (dloc & 7) * 2;
    }
    const float4 v = *reinterpret_cast<const float4*>(src + d0);
    const unsigned h0 = __half_as_ushort(__float2half(v.x));
    const unsigned h1 = __half_as_ushort(__float2half(v.y));
    const unsigned h2 = __half_as_ushort(__float2half(v.z));
    const unsigned h3 = __half_as_ushort(__float2half(v.w));
    uint2 hi;
    hi.x = h0 | (h1 << 16);  hi.y = h2 | (h3 << 16);
    *reinterpret_cast<uint2*>(dh) = hi;

    if (isE) {   // fused ||e||^2 (fp32, exact same reduction as all passing rounds)
        float s = v.x * v.x + v.y * v.y + v.z * v.z + v.w * v.w;
        #pragma unroll
        for (int off = 32; off; off >>= 1) s += __shfl_down(s, off);
        if ((t & 63) == 0) ((float*)(ws + WS_ENORM))[r - N_VEC] = s;
    }
}

// ---------------- kernel 1: fp16 MFMA screen (r12-exact, best measured 84.5 us):
//   A static in LDS, B dbuf 8 KB chunks; single-barrier phase: vmcnt(0) ->
//   s_barrier -> { ds_read | STAGE next | MFMA } compiler-interleaved. ----------------
__global__ __launch_bounds__(256, 2) void vq_mfma_kernel(const char* __restrict__ ws_ro,
                                                         ulonglong2* __restrict__ part2) {
    __shared__ short lds[40960];   // A: [0,32768) shorts (64 KB); B dbuf: [32768,40960) (16 KB)

    const int tid  = threadIdx.x;
    const int lane = tid & 63, wid = tid >> 6;
    const int lane15 = lane & 15, g = lane >> 4;
    const int l7  = lane15 & 7;
    const int c13 = (lane15 >> 1) & 3;
    const int wm = wid >> 1, wn = wid & 1;
    const int bx = blockIdx.x, ksp = blockIdx.y;
    const int row0 = bx * BM;
    const int kbase = ksp * (K_CODES / NSPLIT);

    const char* zh = ws_ro + WS_ZH;
    const char* eh = ws_ro + WS_EH;
    const float* enorm = (const float*)(ws_ro + WS_ENORM);

    #define STAGE_B(kt_, j_)                                                           \
    do {                                                                               \
        const char* sB = eh + (size_t)(((ksp * 8 + (kt_)) * 8) + (j_)) * 8192          \
                            + wid * 2048 + lane * 16;                                  \
        short* dB = lds + 32768 + ((j_) & 1) * 4096 + wid * 1024 + lane * 8;           \
        gload16(sB, dB);                                                               \
        gload16(sB + 1024, dB + 512);                                                  \
    } while (0)

    {
        const char* srcA = zh + (size_t)bx * 65536 + wid * 16384 + lane * 16;
        short* dA = lds + wid * 8192 + lane * 8;
        #pragma unroll
        for (int i = 0; i < 16; ++i) gload16(srcA + i * 1024, dA + i * 512);
    }
    STAGE_B(0, 0);
    float en_c[4], en_n[4];
    #pragma unroll
    for (int n = 0; n < 4; ++n) en_c[n] = enorm[kbase + wn * 64 + n * 16 + lane15];
    asm volatile("s_waitcnt vmcnt(0)" ::: "memory");
    __builtin_amdgcn_s_barrier();
    __builtin_amdgcn_sched_barrier(0);

    int rowterm[4];
    #pragma unroll
    for (int m = 0; m < 4; ++m) rowterm[m] = (wm * 64 + m * 16 + lane15) * 64;
    int colterm[4];
    #pragma unroll
    for (int n = 0; n < 4; ++n) colterm[n] = (wn * 64 + n * 16 + lane15) * 32;
    const int sa0 = (g ^ l7) * 8;
    const int sb  = (g ^ c13) * 8;

    float bestv[16];
    int   bestc[16];
    #pragma unroll
    for (int i = 0; i < 16; ++i) { bestv[i] = 3.0e38f; bestc[i] = 0; }

    #define STEP(j_)                                                                   \
    do {                                                                               \
        asm volatile("s_waitcnt vmcnt(0)" ::: "memory");                               \
        __builtin_amdgcn_s_barrier();                                                  \
        __builtin_amdgcn_sched_barrier(0);                                             \
        f16x8 af[4], bf[4];                                                            \
        const int abase = ((j_) >> 1) * 8192 + (sa0 ^ (((j_) & 1) << 5));              \
        const int bbase = 32768 + ((j_) & 1) * 4096 + sb;                              \
        _Pragma("unroll")                                                              \
        for (int m = 0; m < 4; ++m)                                                    \
            af[m] = *reinterpret_cast<const f16x8*>(lds + abase + rowterm[m]);         \
        _Pragma("unroll")                                                              \
        for (int n = 0; n < 4; ++n)                                                    \
            bf[n] = *reinterpret_cast<const f16x8*>(lds + bbase + colterm[n]);         \
        if ((j_) < 7) {                                                                \
            STAGE_B(kt, (j_) + 1);                                                     \
        } else if (kt < KT_PER - 1) {                                                  \
            STAGE_B(kt + 1, 0);                                                        \
            _Pragma("unroll")                                                          \
            for (int n = 0; n < 4; ++n)                                                \
                en_n[n] = enorm[kbase + (kt + 1) * 128 + wn * 64 + n * 16 + lane15];   \
        }                                                                              \
        __builtin_amdgcn_s_setprio(1);                                                 \
        _Pragma("unroll")                                                              \
        for (int m = 0; m < 4; ++m)                                                    \
            _Pragma("unroll")                                                          \
            for (int n = 0; n < 4; ++n)                                                \
                acc[m][n] = __builtin_amdgcn_mfma_f32_16x16x32_f16(                    \
                    af[m], bf[n], acc[m][n], 0, 0, 0);                                 \
        __builtin_amdgcn_s_setprio(0);                                                 \
    } while (0)

    for (int kt = 0; kt < KT_PER; ++kt) {
        f32x4 acc[4][4];
        #pragma unroll
        for (int m = 0; m < 4; ++m)
            #pragma unroll
            for (int n = 0; n < 4; ++n)
                #pragma unroll
                for (int q = 0; q < 4; ++q) acc[m][n][q] = 0.0f;

        STEP(0); STEP(1); STEP(2); STEP(3);
        STEP(4); STEP(5); STEP(6); STEP(7);

        #pragma unroll
        for (int m = 0; m < 4; ++m)
            #pragma unroll
            for (int n = 0; n < 4; ++n) {
                const int c = kbase + kt * 128 + wn * 64 + n * 16 + lane15;
                #pragma unroll
                for (int q = 0; q < 4; ++q) {
                    const int sl = m * 4 + q;
                    const float s = fmaf(-2.0f, acc[m][n][q], en_c[n]);
                    if (s < bestv[sl]) { bestv[sl] = s; bestc[sl] = c; }
                }
            }
        #pragma unroll
        for (int n = 0; n < 4; ++n) en_c[n] = en_n[n];
    }
    #undef STEP
    #undef STAGE_B

    // tail: per-row top-2 over the 16 lanes sharing each row (lexicographic keys)
    unsigned long long* t2 = reinterpret_cast<unsigned long long*>(lds);  // [wid][64][2]
    #pragma unroll
    for (int sl = 0; sl < 16; ++sl) {
        const int m = sl >> 2, q = sl & 3;
        const unsigned long long k1 = skey(bestv[sl], bestc[sl]);
        unsigned long long m1 = k1;
        #pragma unroll
        for (int msk = 1; msk < 16; msk <<= 1) {
            const unsigned long long o = __shfl_xor(m1, msk);
            m1 = (o < m1) ? o : m1;
        }
        unsigned long long k2 = (k1 == m1) ? ~0ull : k1;
        #pragma unroll
        for (int msk = 1; msk < 16; msk <<= 1) {
            const unsigned long long o = __shfl_xor(k2, msk);
            k2 = (o < k2) ? o : k2;
        }
        if (lane15 == 0) {
            const int row64 = m * 16 + g * 4 + q;
            t2[(wid * 64 + row64) * 2 + 0] = m1;
            t2[(wid * 64 + row64) * 2 + 1] = k2;
        }
    }
    __syncthreads();
    if (tid < 128) {
        const int wm2 = tid >> 6, r64 = tid & 63;
        const unsigned long long a1 = t2[((wm2 * 2 + 0) * 64 + r64) * 2 + 0];
        const unsigned long long a2 = t2[((wm2 * 2 + 0) * 64 + r64) * 2 + 1];
        const unsigned long long b1 = t2[((wm2 * 2 + 1) * 64 + r64) * 2 + 0];
        const unsigned long long b2 = t2[((wm2 * 2 + 1) * 64 + r64) * 2 + 1];
        const unsigned long long r1 = (a1 < b1) ? a1 : b1;
        const unsigned long long hi = (a1 < b1) ? b1 : a1;
        const unsigned long long l2 = (a2 < b2) ? a2 : b2;
        const unsigned long long r2 = (hi < l2) ? hi : l2;
        ulonglong2 res;  res.x = r1;  res.y = r2;
        part2[(size_t)ksp * N_VEC + row0 + tid] = res;
    }
}

// ---------------- kernel 2: merge splits + exact fp64 rescore of global top-4 + loss ----------------
__global__ __launch_bounds__(256) void rescore_kernel(const float* __restrict__ Z,
                                                      const float* __restrict__ E,
                                                      const ulonglong2* __restrict__ part2,
                                                      int* __restrict__ idx_i,
                                                      float* __restrict__ out_idx,
                                                      float* __restrict__ lossp) {
    __shared__ double redl[4];
    const int tid = threadIdx.x, lane = tid & 63, wid = tid >> 6;
    const int r = blockIdx.x * 4 + wid;
    int c0 = 0, c1 = 0, c2 = 0, c3 = 0;
    if (lane == 0) {
        unsigned long long m0 = ~0ull, m1 = ~0ull, m2 = ~0ull, m3 = ~0ull;
        for (int s = 0; s < NSPLIT; ++s) {
            const ulonglong2 p = part2[(size_t)s * N_VEC + r];
            unsigned long long k = p.x;
            if (k < m0) { m3 = m2; m2 = m1; m1 = m0; m0 = k; }
            else if (k < m1) { m3 = m2; m2 = m1; m1 = k; }
            else if (k < m2) { m3 = m2; m2 = k; }
            else if (k < m3) { m3 = k; }
            k = p.y;
            if (k < m0) { m3 = m2; m2 = m1; m1 = m0; m0 = k; }
            else if (k < m1) { m3 = m2; m2 = m1; m1 = k; }
            else if (k < m2) { m3 = m2; m2 = k; }
            else if (k < m3) { m3 = k; }
        }
        c0 = (int)(m0 & 0x1FFFull);  c1 = (int)(m1 & 0x1FFFull);
        c2 = (int)(m2 & 0x1FFFull);  c3 = (int)(m3 & 0x1FFFull);
    }
    c0 = __shfl(c0, 0);  c1 = __shfl(c1, 0);
    c2 = __shfl(c2, 0);  c3 = __shfl(c3, 0);
    const float4 z4 = *reinterpret_cast<const float4*>(Z + (size_t)r * D_DIM + lane * 4);
    double d[4];
    const int cc[4] = {c0, c1, c2, c3};
    #pragma unroll
    for (int j = 0; j < 4; ++j) {
        const float4 e4 = *reinterpret_cast<const float4*>(E + (size_t)cc[j] * D_DIM + lane * 4);
        const double ax = (double)z4.x - (double)e4.x, ay = (double)z4.y - (double)e4.y;
        const double az = (double)z4.z - (double)e4.z, aw = (double)z4.w - (double)e4.w;
        d[j] = ax * ax + ay * ay + az * az + aw * aw;
    }
    #pragma unroll
    for (int off = 1; off < 64; off <<= 1) {
        #pragma unroll
        for (int j = 0; j < 4; ++j) d[j] += __shfl_xor(d[j], off);
    }
    if (lane == 0) {
        double bd = d[0];  int bi = c0;
        #pragma unroll
        for (int j = 1; j < 4; ++j) {
            if (d[j] < bd || (d[j] == bd && cc[j] < bi)) { bd = d[j]; bi = cc[j]; }
        }
        idx_i[r]   = bi;
        out_idx[r] = (float)bi;
        redl[wid]  = bd;            // exact ||z - zq||^2 of the chosen code
    }
    __syncthreads();
    if (tid == 0) lossp[blockIdx.x] = (float)(redl[0] + redl[1] + redl[2] + redl[3]);
}

// ---------------- kernel 3: gather + NCHW transpose ----------------
__global__ __launch_bounds__(256) void gather_kernel(const float* __restrict__ E,
                                                     const int* __restrict__ idx_i,
                                                     float* __restrict__ out) {
    __shared__ float Ls[128 * 65];
    __shared__ int   sIdx[64];

    const int tid = threadIdx.x;
    const int gb  = blockIdx.x;       // 0..255, 64 latent vectors each
    const int n0  = gb * 64;
    const int b   = n0 >> 10;
    const int hwbase = n0 & 1023;

    if (tid < 64) sIdx[tid] = idx_i[n0 + tid];
    __syncthreads();

    for (int h = 0; h < 2; ++h) {
        if (h) __syncthreads();
        const int rowl = tid >> 2;
        const int qs   = tid & 3;
        const float* erow = E + (size_t)sIdx[rowl] * D_DIM + h * 128;
        #pragma unroll
        for (int m = 0; m < 8; ++m) {
            const int c4 = m * 4 + qs;
            const float4 v = *reinterpret_cast<const float4*>(erow + c4 * 4);
            Ls[(c4 * 4 + 0) * 65 + rowl] = v.x;
            Ls[(c4 * 4 + 1) * 65 + rowl] = v.y;
            Ls[(c4 * 4 + 2) * 65 + rowl] = v.z;
            Ls[(c4 * 4 + 3) * 65 + rowl] = v.w;
        }
        __syncthreads();
        const int wl   = tid & 63;
        const int csub = tid >> 6;
        #pragma unroll
        for (int pc = 0; pc < 32; ++pc) {
            const int c_l = pc * 4 + csub;
            const int c   = h * 128 + c_l;
            out[((size_t)(b * 256 + c)) * 1024 + hwbase + wl] = Ls[c_l * 65 + wl];
        }
    }
}

// ---------------- kernel 4: finalize scalars ----------------
__global__ __launch_bounds__(256) void final_kernel(const float* __restrict__ lossp,
                                                    float* __restrict__ out) {
    __shared__ float red[4];
    const int tid = threadIdx.x;
    float s = 0.0f;
    for (int i = tid; i < N_VEC / 4; i += 256) s += lossp[i];
    #pragma unroll
    for (int off = 32; off; off >>= 1) s += __shfl_down(s, off);
    if ((tid & 63) == 0) red[tid >> 6] = s;
    __syncthreads();
    if (tid == 0) {
        const float total = red[0] + red[1] + red[2] + red[3];
        out[DIFF_OFF] = 0.25f * (total / (float)(N_VEC * D_DIM));
        out[PERP_OFF] = 1.0f;
    }
}

// ---------------- launcher ----------------
extern "C" void kernel_launch(void* const* d_in, const int* in_sizes, int n_in,
                              void* d_out, int out_size, void* d_ws, size_t ws_size,
                              hipStream_t stream) {
    const float* Z = (const float*)d_in[0];   // (16,32,32,256) fp32
    const float* E = (const float*)d_in[1];   // (8192,256) fp32
    float* out = (float*)d_out;
    char*  ws  = (char*)d_ws;                 // needs ~14.6 MB

    ulonglong2* part2   = (ulonglong2*)(ws + WS_P2);
    int*        idx_i   = (int*)(ws + WS_IDXI);
    float*      lossbuf = (float*)(ws + WS_LOSS);

    hipLaunchKernelGGL(convert_kernel, dim3((N_VEC + K_CODES) / 4), dim3(256), 0, stream, Z, E, ws);
    hipLaunchKernelGGL(vq_mfma_kernel, dim3(N_VEC / BM, NSPLIT), dim3(256), 0, stream,
                       (const char*)ws, part2);
    hipLaunchKernelGGL(rescore_kernel, dim3(N_VEC / 4), dim3(256), 0, stream,
                       Z, E, part2, idx_i, out + IDX_OFF, lossbuf);
    hipLaunchKernelGGL(gather_kernel, dim3(N_VEC / 64), dim3(256), 0, stream,
                       E, idx_i, out);
    hipLaunchKernelGGL(final_kernel, dim3(1), dim3(256), 0, stream, lossbuf, out);
}